// Round 7
// baseline (193.411 us; speedup 1.0000x reference)
//
#include <hip/hip_runtime.h>
#include <hip/hip_bf16.h>

#define NB  256   // batch B
#define ND  256   // D0 == D1
#define NL  32    // L
#define NH1 128
#define NH2 64

using short8  = __attribute__((ext_vector_type(8))) short;  // 8 bf16 (4 VGPRs)
using short4v = __attribute__((ext_vector_type(4))) short;  // 4 bf16 (2 VGPRs)
using f32x4   = __attribute__((ext_vector_type(4))) float;

static __device__ __forceinline__ short f2bf(float v) {
    __hip_bfloat16 h = __float2bfloat16(v);
    return __builtin_bit_cast(short, h);
}

// ---------------------------------------------------------------------------
// Prep: fp32 weights -> bf16 in d_ws.  W1 stored as two pre-swizzled K-halves
// [128][16 slots] (slot ^= m&7) so mlp staging is a LINEAR copy and swizzled
// reads are bank-balanced (rule #21).  W2 plain.  Also zeroes d_out (replaces
// the hipMemsetAsync dispatch; prep->score are stream-ordered).
// grid 40 x 256 = 10240 units.
// ---------------------------------------------------------------------------
__global__ __launch_bounds__(256) void prep_kernel(
    const float* __restrict__ Wg1, const float* __restrict__ Wg2,
    const float* __restrict__ Wh1, const float* __restrict__ Wh2,
    __hip_bfloat16* __restrict__ w1g, __hip_bfloat16* __restrict__ w1h,
    __hip_bfloat16* __restrict__ w2g, __hip_bfloat16* __restrict__ w2h,
    float* __restrict__ out)
{
    int gid = blockIdx.x * 256 + threadIdx.x;   // 0..10239
    if (gid == 0) out[0] = 0.f;
    const float* src;
    char* dstb;
    if (gid < 8192) {                           // W1: 2 mats x 4096 units
        int mat  = gid >> 12;
        int u    = gid & 4095;
        int half = u >> 11, m = (u >> 4) & 127, s = u & 15;
        src  = (mat ? Wh1 : Wg1) + m * 256 + half * 128 + s * 8;
        dstb = (char*)(mat ? w1h : w1g) + half * 32768 + (m * 16 + (s ^ (m & 7))) * 16;
    } else {                                    // W2: 2 mats x 1024 units
        int g2 = gid - 8192;
        int mat = g2 >> 10, u = g2 & 1023;
        src  = (mat ? Wh2 : Wg2) + u * 8;
        dstb = (char*)(mat ? w2h : w2g) + u * 16;
    }
    f32x4 a = *(const f32x4*)src;
    f32x4 b = *(const f32x4*)(src + 4);
    short8 o;
#pragma unroll
    for (int q = 0; q < 4; ++q) { o[q] = f2bf(a[q]); o[4 + q] = f2bf(b[q]); }
    *(short8*)dstb = o;
}

// ---------------------------------------------------------------------------
// Kernel A: per-batch MLP via bf16 MFMA.  grid = 512 (256 x + 256 y), 256 thr.
// LDS 56KB: W1half[32K] @0, xT[16K] @32768, h1T[8K] @49152 -> 2 blocks/CU.
// GEMM1: [128,32,K=256] (K-halved W1 staging); GEMM2: [64,32,K=128].
// Output bf16 [L][B][H2].  (UNCHANGED from round 6 — passed, absmax 0.0.)
// ---------------------------------------------------------------------------
__global__ __launch_bounds__(256, 2) void mlp_kernel(
    const float* __restrict__ x, const float* __restrict__ y,
    const float* __restrict__ bg1, const float* __restrict__ bg2,
    const float* __restrict__ bh1, const float* __restrict__ bh2,
    const __hip_bfloat16* __restrict__ w1g, const __hip_bfloat16* __restrict__ w1h,
    const __hip_bfloat16* __restrict__ w2g, const __hip_bfloat16* __restrict__ w2h,
    __hip_bfloat16* __restrict__ xg, __hip_bfloat16* __restrict__ yh)
{
    __shared__ char lds[57344];
    const int tid  = threadIdx.x;
    const int lane = tid & 63, w = tid >> 6;
    const int lc   = lane & 15, lg = lane >> 4;
    const int bb   = blockIdx.x & (NB - 1);
    const bool isY = blockIdx.x >= NB;

    const float* __restrict__ Xin = (isY ? y : x) + (size_t)bb * (ND * NL);
    const float* __restrict__ B1  = isY ? bh1 : bg1;
    const float* __restrict__ B2  = isY ? bh2 : bg2;
    const __hip_bfloat16* __restrict__ W1 = isY ? w1h : w1g;  // swizzled halves
    const __hip_bfloat16* __restrict__ W2 = isY ? w2h : w2g;  // plain
    __hip_bfloat16* __restrict__ Out = isY ? yh : xg;

    // W2 A-frags (rows m = w*16+lc) direct global->reg, issued early
    short8 w2frag[4];
#pragma unroll
    for (int ks = 0; ks < 4; ++ks)
        w2frag[ks] = *(const short8*)(W2 + (w * 16 + lc) * NH1 + ks * 32 + lg * 8);

    // stage W1 lo-half: linear 32KB copy (source pre-swizzled)
    {
        const short8* s8 = (const short8*)W1;
        short8* d8 = (short8*)lds;
#pragma unroll
        for (int it = 0; it < 8; ++it) d8[it * 256 + tid] = s8[it * 256 + tid];
    }
    // stage xT [l=32][k=256] bf16, rows 512B, slot-swizzle ^(l&7).
    {
        const int l = tid & 31;
        const int c0b = (tid >> 5) * 8;
#pragma unroll
        for (int it = 0; it < 4; ++it) {
            int c0 = c0b + it * 64;
            float v[8];
#pragma unroll
            for (int q = 0; q < 8; ++q) v[q] = Xin[(c0 + q) * NL + l];
            short8 o;
#pragma unroll
            for (int q = 0; q < 8; ++q) o[q] = f2bf(v[q]);
            *(short8*)(lds + 32768 + l * 512 + (((c0 >> 3) ^ (l & 7)) * 16)) = o;
        }
    }
    __syncthreads();

    // GEMM1: h1 = W1 @ xT^T ; acc across both K-halves
    f32x4 acc1[2][2] = {};   // [mt][nt]
#pragma unroll
    for (int half = 0; half < 2; ++half) {
        if (half) {
            __syncthreads();             // all waves done reading lo-half
            const short8* s8 = (const short8*)W1 + 2048;
            short8* d8 = (short8*)lds;
#pragma unroll
            for (int it = 0; it < 8; ++it) d8[it * 256 + tid] = s8[it * 256 + tid];
            __syncthreads();
        }
#pragma unroll
        for (int ks = 0; ks < 4; ++ks) {
            short8 a[2], b[2];
#pragma unroll
            for (int mt = 0; mt < 2; ++mt) {
                int m = w * 32 + mt * 16 + lc;
                a[mt] = *(const short8*)(lds + m * 256 + (((ks * 4 + lg) ^ (m & 7)) * 16));
            }
#pragma unroll
            for (int nt = 0; nt < 2; ++nt) {
                int n = nt * 16 + lc;
                int slot = half * 16 + ks * 4 + lg;
                b[nt] = *(const short8*)(lds + 32768 + n * 512 + ((slot ^ (n & 7)) * 16));
            }
#pragma unroll
            for (int mt = 0; mt < 2; ++mt)
#pragma unroll
                for (int nt = 0; nt < 2; ++nt)
                    acc1[mt][nt] = __builtin_amdgcn_mfma_f32_16x16x32_bf16(
                        a[mt], b[nt], acc1[mt][nt], 0, 0, 0);
        }
    }

    // bias1 + relu + pack -> h1T [n=32][k=128] bf16, rows 256B, swizzled.
    {
#pragma unroll
        for (int mt = 0; mt < 2; ++mt) {
            int mbase = w * 32 + mt * 16 + lg * 4;       // D row = lg*4+r
            f32x4 bv = *(const f32x4*)(B1 + mbase);
#pragma unroll
            for (int nt = 0; nt < 2; ++nt) {
                int n = nt * 16 + lc;                    // D col
                short4v o;
#pragma unroll
                for (int r = 0; r < 4; ++r) {
                    float vv = acc1[mt][nt][r] + bv[r];
                    o[r] = f2bf(vv > 0.f ? vv : 0.f);
                }
                int byte = 49152 + n * 256 + (((mbase >> 3) ^ (n & 7)) * 16) + (mbase & 7) * 2;
                *(short4v*)(lds + byte) = o;
            }
        }
    }
    __syncthreads();

    // GEMM2: out2 = W2 @ h1 ; A from regs, B from h1T
    f32x4 acc2[2] = {};
#pragma unroll
    for (int ks = 0; ks < 4; ++ks) {
#pragma unroll
        for (int nt = 0; nt < 2; ++nt) {
            int n = nt * 16 + lc;
            short8 b = *(const short8*)(lds + 49152 + n * 256 + (((ks * 4 + lg) ^ (n & 7)) * 16));
            acc2[nt] = __builtin_amdgcn_mfma_f32_16x16x32_bf16(
                w2frag[ks], b, acc2[nt], 0, 0, 0);
        }
    }
    // bias2 + store bf16 [L][B][H2]
    {
        int mbase = w * 16 + lg * 4;
        f32x4 bv = *(const f32x4*)(B2 + mbase);
#pragma unroll
        for (int nt = 0; nt < 2; ++nt) {
            int l = nt * 16 + lc;
            short4v o;
#pragma unroll
            for (int r = 0; r < 4; ++r) o[r] = f2bf(acc2[nt][r] + bv[r]);
            *(short4v*)((char*)Out + (((size_t)l * NB + bb) * NH2 + mbase) * 2) = o;
        }
    }
}

// ---------------------------------------------------------------------------
// Kernel B: per (i,j) pair, S = Yj @ Xi^T (256x256, K=64) via bf16 MFMA,
// streamed exp-sum over q-panels + diag extraction.  grid = 1024, block = 256.
// R7: Yj staging dropped — afrag rows are single-use, loaded direct from
// global (16B/lane, L2-resident).  LDS 32KB (Xi only) -> 4 blocks/CU.
// ---------------------------------------------------------------------------
__global__ __launch_bounds__(256, 4) void score_kernel(
    const __hip_bfloat16* __restrict__ xg,   // [L][B][H2]
    const __hip_bfloat16* __restrict__ yh,   // [L][B][H2]
    float* __restrict__ out)
{
    __shared__ short tiles[NB * NH2];        // Xi only, swizzled (32KB)
    __shared__ float red[4];

    const int tid  = threadIdx.x;
    const int lane = tid & 63;
    const int w    = tid >> 6;               // wave 0..3 -> p rows [w*64, w*64+64)
    const int i    = blockIdx.x & (NL - 1);
    const int j    = blockIdx.x >> 5;
    const int lc   = lane & 15, lg = lane >> 4;

    // A-fragments (Yj rows, single-use): direct global->reg, issued first
    const char* Yg = (const char*)(yh + (size_t)j * (NB * NH2));
    short8 afrag[4][2];
#pragma unroll
    for (int mt = 0; mt < 4; ++mt) {
        int row = w * 64 + mt * 16 + lc;
#pragma unroll
        for (int ks = 0; ks < 2; ++ks)
            afrag[mt][ks] = *(const short8*)(Yg + row * 128 + ks * 64 + lg * 16);
    }

    // stage Xi tile (32KB) with XOR swizzle (row stride 128B -> G4 fix)
    {
        const short8* sx = (const short8*)(xg + (size_t)i * (NB * NH2));
        char* xb = (char*)tiles;
#pragma unroll
        for (int it = 0; it < 8; ++it) {
            int u   = it * 256 + tid;               // 16B unit, 0..2047
            int row = u >> 3;
            int swz = (u * 16) ^ ((row & 7) << 4);
            *(short8*)(xb + swz) = sx[u];
        }
    }
    __syncthreads();

    const char* Xbase = (const char*)tiles;

    float rowsum[4][4] = {};   // [mt][r], per-lane partial over owned cols
    float diag_acc = 0.f;

#pragma unroll
    for (int pn = 0; pn < 4; ++pn) {         // q-panel: cols [pn*64, pn*64+64)
        f32x4 acc[4][4] = {};                // [mt][nt]
#pragma unroll
        for (int nt = 0; nt < 4; ++nt) {
            int row = pn * 64 + nt * 16 + lc;  // Xi row = q
#pragma unroll
            for (int ks = 0; ks < 2; ++ks) {
                int byte = (row * 128 + ks * 64 + lg * 16) ^ ((row & 7) << 4);
                short8 bfrag = *(const short8*)(Xbase + byte);
#pragma unroll
                for (int mt = 0; mt < 4; ++mt)
                    acc[mt][nt] = __builtin_amdgcn_mfma_f32_16x16x32_bf16(
                        afrag[mt][ks], bfrag, acc[mt][nt], 0, 0, 0);
            }
        }
        // streamed exp-sum (no max subtraction: S is O(1), fp32-safe)
#pragma unroll
        for (int mt = 0; mt < 4; ++mt)
#pragma unroll
            for (int r = 0; r < 4; ++r) {
                float s = 0.f;
#pragma unroll
                for (int nt = 0; nt < 4; ++nt) s += __expf(acc[mt][nt][r]);
                rowsum[mt][r] += s;
            }
        // diag (p==q): only when this wave's row range == panel col range
        if (pn == w) {
#pragma unroll
            for (int mt = 0; mt < 4; ++mt)
#pragma unroll
                for (int r = 0; r < 4; ++r)
                    if (lc == lg * 4 + r) diag_acc += acc[mt][mt][r];
        }
    }

    // finish lse: reduce rowsum across the 16 col-lanes, then -log
    float neglog = 0.f;
#pragma unroll
    for (int mt = 0; mt < 4; ++mt)
#pragma unroll
        for (int r = 0; r < 4; ++r) {
            float v = rowsum[mt][r];
            v += __shfl_xor(v, 1);
            v += __shfl_xor(v, 2);
            v += __shfl_xor(v, 4);
            v += __shfl_xor(v, 8);
            neglog -= __logf(v);
        }
    float local = diag_acc + (lc == 0 ? neglog : 0.f);
    // wave reduce (64 lanes)
#pragma unroll
    for (int m = 32; m; m >>= 1) local += __shfl_xor(local, m);
    if (lane == 0) red[w] = local;
    __syncthreads();
    if (tid == 0) {
        float total = red[0] + red[1] + red[2] + red[3];
        float val = total * (1.0f / (1024.0f * 256.0f));
        if (blockIdx.x == 0) val += logf(256.0f);
        atomicAdd(out, val);
    }
}

// ---------------------------------------------------------------------------
extern "C" void kernel_launch(void* const* d_in, const int* in_sizes, int n_in,
                              void* d_out, int out_size, void* d_ws, size_t ws_size,
                              hipStream_t stream)
{
    (void)in_sizes; (void)n_in; (void)out_size; (void)ws_size;
    const float* x   = (const float*)d_in[0];
    const float* y   = (const float*)d_in[1];
    const float* Wg1 = (const float*)d_in[2];
    const float* bg1 = (const float*)d_in[3];
    const float* Wg2 = (const float*)d_in[4];
    const float* bg2 = (const float*)d_in[5];
    const float* Wh1 = (const float*)d_in[6];
    const float* bh1 = (const float*)d_in[7];
    const float* Wh2 = (const float*)d_in[8];
    const float* bh2 = (const float*)d_in[9];

    char* ws = (char*)d_ws;
    __hip_bfloat16* xg  = (__hip_bfloat16*)ws;                    // 1MB
    __hip_bfloat16* yh  = (__hip_bfloat16*)(ws + (1 << 20));      // 1MB
    __hip_bfloat16* w1g = (__hip_bfloat16*)(ws + (2 << 20));      // 64KB (swizzled halves)
    __hip_bfloat16* w1h = (__hip_bfloat16*)(ws + (2 << 20) + 65536);
    __hip_bfloat16* w2g = (__hip_bfloat16*)(ws + (2 << 20) + 131072);  // 16KB plain
    __hip_bfloat16* w2h = (__hip_bfloat16*)(ws + (2 << 20) + 147456);
    float* out = (float*)d_out;

    prep_kernel<<<dim3(40), dim3(256), 0, stream>>>(
        Wg1, Wg2, Wh1, Wh2, w1g, w1h, w2g, w2h, out);
    mlp_kernel<<<dim3(512), dim3(256), 0, stream>>>(
        x, y, bg1, bg2, bh1, bh2, w1g, w1h, w2g, w2h, xg, yh);
    score_kernel<<<dim3(1024), dim3(256), 0, stream>>>(xg, yh, out);
}

// Round 8
// 113.405 us; speedup vs baseline: 1.7055x; 1.7055x over previous
//
#include <hip/hip_runtime.h>
#include <hip/hip_bf16.h>

#define NB  256   // batch B
#define ND  256   // D0 == D1
#define NL  32    // L
#define NH1 128
#define NH2 64

using short8  = __attribute__((ext_vector_type(8))) short;  // 8 bf16 (4 VGPRs)
using short4v = __attribute__((ext_vector_type(4))) short;  // 4 bf16 (2 VGPRs)
using f32x4   = __attribute__((ext_vector_type(4))) float;

static __device__ __forceinline__ short f2bf(float v) {
    __hip_bfloat16 h = __float2bfloat16(v);
    return __builtin_bit_cast(short, h);
}

// ---------------------------------------------------------------------------
// Prep: fp32 weights -> bf16 in d_ws.  W1 stored as two pre-swizzled K-halves
// [128][16 slots] (slot ^= m&7) so mlp staging is a LINEAR copy and swizzled
// reads are bank-balanced (rule #21).  W2 plain.  Also zeroes d_out (replaces
// the hipMemsetAsync dispatch; prep->score are stream-ordered).
// grid 40 x 256 = 10240 units.
// ---------------------------------------------------------------------------
__global__ __launch_bounds__(256) void prep_kernel(
    const float* __restrict__ Wg1, const float* __restrict__ Wg2,
    const float* __restrict__ Wh1, const float* __restrict__ Wh2,
    __hip_bfloat16* __restrict__ w1g, __hip_bfloat16* __restrict__ w1h,
    __hip_bfloat16* __restrict__ w2g, __hip_bfloat16* __restrict__ w2h,
    float* __restrict__ out)
{
    int gid = blockIdx.x * 256 + threadIdx.x;   // 0..10239
    if (gid == 0) out[0] = 0.f;
    const float* src;
    char* dstb;
    if (gid < 8192) {                           // W1: 2 mats x 4096 units
        int mat  = gid >> 12;
        int u    = gid & 4095;
        int half = u >> 11, m = (u >> 4) & 127, s = u & 15;
        src  = (mat ? Wh1 : Wg1) + m * 256 + half * 128 + s * 8;
        dstb = (char*)(mat ? w1h : w1g) + half * 32768 + (m * 16 + (s ^ (m & 7))) * 16;
    } else {                                    // W2: 2 mats x 1024 units
        int g2 = gid - 8192;
        int mat = g2 >> 10, u = g2 & 1023;
        src  = (mat ? Wh2 : Wg2) + u * 8;
        dstb = (char*)(mat ? w2h : w2g) + u * 16;
    }
    f32x4 a = *(const f32x4*)src;
    f32x4 b = *(const f32x4*)(src + 4);
    short8 o;
#pragma unroll
    for (int q = 0; q < 4; ++q) { o[q] = f2bf(a[q]); o[4 + q] = f2bf(b[q]); }
    *(short8*)dstb = o;
}

// ---------------------------------------------------------------------------
// Kernel A: per-batch MLP via bf16 MFMA.  grid = 512 (256 x + 256 y), 256 thr.
// LDS 56KB: W1half[32K] @0, xT[16K] @32768, h1T[8K] @49152 -> 2 blocks/CU.
// GEMM1: [128,32,K=256] (K-halved W1 staging); GEMM2: [64,32,K=128].
// Output bf16 [L][B][H2].  (UNCHANGED from round 6 — passed, absmax 0.0.)
// ---------------------------------------------------------------------------
__global__ __launch_bounds__(256, 2) void mlp_kernel(
    const float* __restrict__ x, const float* __restrict__ y,
    const float* __restrict__ bg1, const float* __restrict__ bg2,
    const float* __restrict__ bh1, const float* __restrict__ bh2,
    const __hip_bfloat16* __restrict__ w1g, const __hip_bfloat16* __restrict__ w1h,
    const __hip_bfloat16* __restrict__ w2g, const __hip_bfloat16* __restrict__ w2h,
    __hip_bfloat16* __restrict__ xg, __hip_bfloat16* __restrict__ yh)
{
    __shared__ char lds[57344];
    const int tid  = threadIdx.x;
    const int lane = tid & 63, w = tid >> 6;
    const int lc   = lane & 15, lg = lane >> 4;
    const int bb   = blockIdx.x & (NB - 1);
    const bool isY = blockIdx.x >= NB;

    const float* __restrict__ Xin = (isY ? y : x) + (size_t)bb * (ND * NL);
    const float* __restrict__ B1  = isY ? bh1 : bg1;
    const float* __restrict__ B2  = isY ? bh2 : bg2;
    const __hip_bfloat16* __restrict__ W1 = isY ? w1h : w1g;  // swizzled halves
    const __hip_bfloat16* __restrict__ W2 = isY ? w2h : w2g;  // plain
    __hip_bfloat16* __restrict__ Out = isY ? yh : xg;

    // W2 A-frags (rows m = w*16+lc) direct global->reg, issued early
    short8 w2frag[4];
#pragma unroll
    for (int ks = 0; ks < 4; ++ks)
        w2frag[ks] = *(const short8*)(W2 + (w * 16 + lc) * NH1 + ks * 32 + lg * 8);

    // stage W1 lo-half: linear 32KB copy (source pre-swizzled)
    {
        const short8* s8 = (const short8*)W1;
        short8* d8 = (short8*)lds;
#pragma unroll
        for (int it = 0; it < 8; ++it) d8[it * 256 + tid] = s8[it * 256 + tid];
    }
    // stage xT [l=32][k=256] bf16, rows 512B, slot-swizzle ^(l&7).
    {
        const int l = tid & 31;
        const int c0b = (tid >> 5) * 8;
#pragma unroll
        for (int it = 0; it < 4; ++it) {
            int c0 = c0b + it * 64;
            float v[8];
#pragma unroll
            for (int q = 0; q < 8; ++q) v[q] = Xin[(c0 + q) * NL + l];
            short8 o;
#pragma unroll
            for (int q = 0; q < 8; ++q) o[q] = f2bf(v[q]);
            *(short8*)(lds + 32768 + l * 512 + (((c0 >> 3) ^ (l & 7)) * 16)) = o;
        }
    }
    __syncthreads();

    // GEMM1: h1 = W1 @ xT^T ; acc across both K-halves
    f32x4 acc1[2][2] = {};   // [mt][nt]
#pragma unroll
    for (int half = 0; half < 2; ++half) {
        if (half) {
            __syncthreads();             // all waves done reading lo-half
            const short8* s8 = (const short8*)W1 + 2048;
            short8* d8 = (short8*)lds;
#pragma unroll
            for (int it = 0; it < 8; ++it) d8[it * 256 + tid] = s8[it * 256 + tid];
            __syncthreads();
        }
#pragma unroll
        for (int ks = 0; ks < 4; ++ks) {
            short8 a[2], b[2];
#pragma unroll
            for (int mt = 0; mt < 2; ++mt) {
                int m = w * 32 + mt * 16 + lc;
                a[mt] = *(const short8*)(lds + m * 256 + (((ks * 4 + lg) ^ (m & 7)) * 16));
            }
#pragma unroll
            for (int nt = 0; nt < 2; ++nt) {
                int n = nt * 16 + lc;
                int slot = half * 16 + ks * 4 + lg;
                b[nt] = *(const short8*)(lds + 32768 + n * 512 + ((slot ^ (n & 7)) * 16));
            }
#pragma unroll
            for (int mt = 0; mt < 2; ++mt)
#pragma unroll
                for (int nt = 0; nt < 2; ++nt)
                    acc1[mt][nt] = __builtin_amdgcn_mfma_f32_16x16x32_bf16(
                        a[mt], b[nt], acc1[mt][nt], 0, 0, 0);
        }
    }

    // bias1 + relu + pack -> h1T [n=32][k=128] bf16, rows 256B, swizzled.
    {
#pragma unroll
        for (int mt = 0; mt < 2; ++mt) {
            int mbase = w * 32 + mt * 16 + lg * 4;       // D row = lg*4+r
            f32x4 bv = *(const f32x4*)(B1 + mbase);
#pragma unroll
            for (int nt = 0; nt < 2; ++nt) {
                int n = nt * 16 + lc;                    // D col
                short4v o;
#pragma unroll
                for (int r = 0; r < 4; ++r) {
                    float vv = acc1[mt][nt][r] + bv[r];
                    o[r] = f2bf(vv > 0.f ? vv : 0.f);
                }
                int byte = 49152 + n * 256 + (((mbase >> 3) ^ (n & 7)) * 16) + (mbase & 7) * 2;
                *(short4v*)(lds + byte) = o;
            }
        }
    }
    __syncthreads();

    // GEMM2: out2 = W2 @ h1 ; A from regs, B from h1T
    f32x4 acc2[2] = {};
#pragma unroll
    for (int ks = 0; ks < 4; ++ks) {
#pragma unroll
        for (int nt = 0; nt < 2; ++nt) {
            int n = nt * 16 + lc;
            short8 b = *(const short8*)(lds + 49152 + n * 256 + (((ks * 4 + lg) ^ (n & 7)) * 16));
            acc2[nt] = __builtin_amdgcn_mfma_f32_16x16x32_bf16(
                w2frag[ks], b, acc2[nt], 0, 0, 0);
        }
    }
    // bias2 + store bf16 [L][B][H2]
    {
        int mbase = w * 16 + lg * 4;
        f32x4 bv = *(const f32x4*)(B2 + mbase);
#pragma unroll
        for (int nt = 0; nt < 2; ++nt) {
            int l = nt * 16 + lc;
            short4v o;
#pragma unroll
            for (int r = 0; r < 4; ++r) o[r] = f2bf(acc2[nt][r] + bv[r]);
            *(short4v*)((char*)Out + (((size_t)l * NB + bb) * NH2 + mbase) * 2) = o;
        }
    }
}

// ---------------------------------------------------------------------------
// Kernel B: per (i,j) pair, S = Yj @ Xi^T (256x256, K=64) via bf16 MFMA,
// streamed exp-sum over q-panels + diag extraction.  grid = 1024, block = 256.
// REVERTED to the round-6 version (both tiles LDS-staged, 2 blocks/CU):
// R7's (256,4) cap forced ~150 live VGPRs into 128 -> scratch spills
// (FETCH 121MB / WRITE 232MB of spill traffic, 124us).  Known-good here.
// ---------------------------------------------------------------------------
__global__ __launch_bounds__(256, 2) void score_kernel(
    const __hip_bfloat16* __restrict__ xg,   // [L][B][H2]
    const __hip_bfloat16* __restrict__ yh,   // [L][B][H2]
    float* __restrict__ out)
{
    __shared__ short tiles[2 * NB * NH2];    // Xi @ 0, Yj @ +32KB (swizzled)
    __shared__ float red[4];

    const int tid  = threadIdx.x;
    const int lane = tid & 63;
    const int w    = tid >> 6;               // wave 0..3 -> p rows [w*64, w*64+64)
    const int i    = blockIdx.x & (NL - 1);
    const int j    = blockIdx.x >> 5;

    {
        const short8* sx = (const short8*)(xg + (size_t)i * (NB * NH2));
        const short8* sy = (const short8*)(yh + (size_t)j * (NB * NH2));
        char* xb = (char*)tiles;
        char* yb = (char*)(tiles + NB * NH2);
#pragma unroll
        for (int it = 0; it < 8; ++it) {
            int u   = it * 256 + tid;               // 16B unit, 0..2047
            int row = u >> 3;
            int swz = (u * 16) ^ ((row & 7) << 4);
            *(short8*)(xb + swz) = sx[u];
            *(short8*)(yb + swz) = sy[u];
        }
    }
    __syncthreads();

    const char* Xbase = (const char*)tiles;
    const char* Ybase = (const char*)(tiles + NB * NH2);
    const int lc = lane & 15, lg = lane >> 4;

    short8 afrag[4][2];
#pragma unroll
    for (int mt = 0; mt < 4; ++mt) {
        int row = w * 64 + mt * 16 + lc;
#pragma unroll
        for (int ks = 0; ks < 2; ++ks) {
            int byte = (row * 128 + ks * 64 + lg * 16) ^ ((row & 7) << 4);
            afrag[mt][ks] = *(const short8*)(Ybase + byte);
        }
    }

    float rowsum[4][4] = {};
    float diag_acc = 0.f;

#pragma unroll
    for (int pn = 0; pn < 4; ++pn) {
        f32x4 acc[4][4] = {};
#pragma unroll
        for (int nt = 0; nt < 4; ++nt) {
            int row = pn * 64 + nt * 16 + lc;
#pragma unroll
            for (int ks = 0; ks < 2; ++ks) {
                int byte = (row * 128 + ks * 64 + lg * 16) ^ ((row & 7) << 4);
                short8 bfrag = *(const short8*)(Xbase + byte);
#pragma unroll
                for (int mt = 0; mt < 4; ++mt)
                    acc[mt][nt] = __builtin_amdgcn_mfma_f32_16x16x32_bf16(
                        afrag[mt][ks], bfrag, acc[mt][nt], 0, 0, 0);
            }
        }
#pragma unroll
        for (int mt = 0; mt < 4; ++mt)
#pragma unroll
            for (int r = 0; r < 4; ++r) {
                float s = 0.f;
#pragma unroll
                for (int nt = 0; nt < 4; ++nt) s += __expf(acc[mt][nt][r]);
                rowsum[mt][r] += s;
            }
        if (pn == w) {
#pragma unroll
            for (int mt = 0; mt < 4; ++mt)
#pragma unroll
                for (int r = 0; r < 4; ++r)
                    if (lc == lg * 4 + r) diag_acc += acc[mt][mt][r];
        }
    }

    float neglog = 0.f;
#pragma unroll
    for (int mt = 0; mt < 4; ++mt)
#pragma unroll
        for (int r = 0; r < 4; ++r) {
            float v = rowsum[mt][r];
            v += __shfl_xor(v, 1);
            v += __shfl_xor(v, 2);
            v += __shfl_xor(v, 4);
            v += __shfl_xor(v, 8);
            neglog -= __logf(v);
        }
    float local = diag_acc + (lc == 0 ? neglog : 0.f);
#pragma unroll
    for (int m = 32; m; m >>= 1) local += __shfl_xor(local, m);
    if (lane == 0) red[w] = local;
    __syncthreads();
    if (tid == 0) {
        float total = red[0] + red[1] + red[2] + red[3];
        float val = total * (1.0f / (1024.0f * 256.0f));
        if (blockIdx.x == 0) val += logf(256.0f);
        atomicAdd(out, val);
    }
}

// ---------------------------------------------------------------------------
extern "C" void kernel_launch(void* const* d_in, const int* in_sizes, int n_in,
                              void* d_out, int out_size, void* d_ws, size_t ws_size,
                              hipStream_t stream)
{
    (void)in_sizes; (void)n_in; (void)out_size; (void)ws_size;
    const float* x   = (const float*)d_in[0];
    const float* y   = (const float*)d_in[1];
    const float* Wg1 = (const float*)d_in[2];
    const float* bg1 = (const float*)d_in[3];
    const float* Wg2 = (const float*)d_in[4];
    const float* bg2 = (const float*)d_in[5];
    const float* Wh1 = (const float*)d_in[6];
    const float* bh1 = (const float*)d_in[7];
    const float* Wh2 = (const float*)d_in[8];
    const float* bh2 = (const float*)d_in[9];

    char* ws = (char*)d_ws;
    __hip_bfloat16* xg  = (__hip_bfloat16*)ws;                    // 1MB
    __hip_bfloat16* yh  = (__hip_bfloat16*)(ws + (1 << 20));      // 1MB
    __hip_bfloat16* w1g = (__hip_bfloat16*)(ws + (2 << 20));      // 64KB (swizzled halves)
    __hip_bfloat16* w1h = (__hip_bfloat16*)(ws + (2 << 20) + 65536);
    __hip_bfloat16* w2g = (__hip_bfloat16*)(ws + (2 << 20) + 131072);  // 16KB plain
    __hip_bfloat16* w2h = (__hip_bfloat16*)(ws + (2 << 20) + 147456);
    float* out = (float*)d_out;

    prep_kernel<<<dim3(40), dim3(256), 0, stream>>>(
        Wg1, Wg2, Wh1, Wh2, w1g, w1h, w2g, w2h, out);
    mlp_kernel<<<dim3(512), dim3(256), 0, stream>>>(
        x, y, bg1, bg2, bh1, bh2, w1g, w1h, w2g, w2h, xg, yh);
    score_kernel<<<dim3(1024), dim3(256), 0, stream>>>(xg, yh, out);
}

// Round 11
// 111.454 us; speedup vs baseline: 1.7353x; 1.0175x over previous
//
#include <hip/hip_runtime.h>
#include <hip/hip_bf16.h>

#define NB  256   // batch B
#define ND  256   // D0 == D1
#define NL  32    // L
#define NH1 128
#define NH2 64

using short8  = __attribute__((ext_vector_type(8))) short;  // 8 bf16 (4 VGPRs)
using short4v = __attribute__((ext_vector_type(4))) short;  // 4 bf16 (2 VGPRs)
using f32x4   = __attribute__((ext_vector_type(4))) float;

static __device__ __forceinline__ short f2bf(float v) {
    __hip_bfloat16 h = __float2bfloat16(v);
    return __builtin_bit_cast(short, h);
}

// ---------------------------------------------------------------------------
// Prep: fp32 weights -> bf16 in d_ws.  W1 stored as two pre-swizzled K-halves
// [128][16 slots] (slot ^= m&7) so mlp staging is a LINEAR copy and swizzled
// reads are bank-balanced (rule #21).  W2 plain.  grid 40 x 256 = 10240 units.
// ---------------------------------------------------------------------------
__global__ __launch_bounds__(256) void prep_kernel(
    const float* __restrict__ Wg1, const float* __restrict__ Wg2,
    const float* __restrict__ Wh1, const float* __restrict__ Wh2,
    __hip_bfloat16* __restrict__ w1g, __hip_bfloat16* __restrict__ w1h,
    __hip_bfloat16* __restrict__ w2g, __hip_bfloat16* __restrict__ w2h)
{
    int gid = blockIdx.x * 256 + threadIdx.x;   // 0..10239
    const float* src;
    char* dstb;
    if (gid < 8192) {                           // W1: 2 mats x 4096 units
        int mat  = gid >> 12;
        int u    = gid & 4095;
        int half = u >> 11, m = (u >> 4) & 127, s = u & 15;
        src  = (mat ? Wh1 : Wg1) + m * 256 + half * 128 + s * 8;
        dstb = (char*)(mat ? w1h : w1g) + half * 32768 + (m * 16 + (s ^ (m & 7))) * 16;
    } else {                                    // W2: 2 mats x 1024 units
        int g2 = gid - 8192;
        int mat = g2 >> 10, u = g2 & 1023;
        src  = (mat ? Wh2 : Wg2) + u * 8;
        dstb = (char*)(mat ? w2h : w2g) + u * 16;
    }
    f32x4 a = *(const f32x4*)src;
    f32x4 b = *(const f32x4*)(src + 4);
    short8 o;
#pragma unroll
    for (int q = 0; q < 4; ++q) { o[q] = f2bf(a[q]); o[4 + q] = f2bf(b[q]); }
    *(short8*)dstb = o;
}

// ---------------------------------------------------------------------------
// Kernel A: per-batch MLP via bf16 MFMA.  grid = 512 (256 x + 256 y), 256 thr.
// LDS 56KB: W1half[32K] @0, xT[16K] @32768, h1T[8K] @49152 -> 2 blocks/CU.
// GEMM1: [128,32,K=256] (K-halved W1 staging); GEMM2: [64,32,K=128].
// Output bf16 [L][B][H2].  (UNCHANGED — passed, absmax 0.0.)
// ---------------------------------------------------------------------------
__global__ __launch_bounds__(256, 2) void mlp_kernel(
    const float* __restrict__ x, const float* __restrict__ y,
    const float* __restrict__ bg1, const float* __restrict__ bg2,
    const float* __restrict__ bh1, const float* __restrict__ bh2,
    const __hip_bfloat16* __restrict__ w1g, const __hip_bfloat16* __restrict__ w1h,
    const __hip_bfloat16* __restrict__ w2g, const __hip_bfloat16* __restrict__ w2h,
    __hip_bfloat16* __restrict__ xg, __hip_bfloat16* __restrict__ yh)
{
    __shared__ char lds[57344];
    const int tid  = threadIdx.x;
    const int lane = tid & 63, w = tid >> 6;
    const int lc   = lane & 15, lg = lane >> 4;
    const int bb   = blockIdx.x & (NB - 1);
    const bool isY = blockIdx.x >= NB;

    const float* __restrict__ Xin = (isY ? y : x) + (size_t)bb * (ND * NL);
    const float* __restrict__ B1  = isY ? bh1 : bg1;
    const float* __restrict__ B2  = isY ? bh2 : bg2;
    const __hip_bfloat16* __restrict__ W1 = isY ? w1h : w1g;  // swizzled halves
    const __hip_bfloat16* __restrict__ W2 = isY ? w2h : w2g;  // plain
    __hip_bfloat16* __restrict__ Out = isY ? yh : xg;

    // W2 A-frags (rows m = w*16+lc) direct global->reg, issued early
    short8 w2frag[4];
#pragma unroll
    for (int ks = 0; ks < 4; ++ks)
        w2frag[ks] = *(const short8*)(W2 + (w * 16 + lc) * NH1 + ks * 32 + lg * 8);

    // stage W1 lo-half: linear 32KB copy (source pre-swizzled)
    {
        const short8* s8 = (const short8*)W1;
        short8* d8 = (short8*)lds;
#pragma unroll
        for (int it = 0; it < 8; ++it) d8[it * 256 + tid] = s8[it * 256 + tid];
    }
    // stage xT [l=32][k=256] bf16, rows 512B, slot-swizzle ^(l&7).
    {
        const int l = tid & 31;
        const int c0b = (tid >> 5) * 8;
#pragma unroll
        for (int it = 0; it < 4; ++it) {
            int c0 = c0b + it * 64;
            float v[8];
#pragma unroll
            for (int q = 0; q < 8; ++q) v[q] = Xin[(c0 + q) * NL + l];
            short8 o;
#pragma unroll
            for (int q = 0; q < 8; ++q) o[q] = f2bf(v[q]);
            *(short8*)(lds + 32768 + l * 512 + (((c0 >> 3) ^ (l & 7)) * 16)) = o;
        }
    }
    __syncthreads();

    // GEMM1: h1 = W1 @ xT^T ; acc across both K-halves
    f32x4 acc1[2][2] = {};   // [mt][nt]
#pragma unroll
    for (int half = 0; half < 2; ++half) {
        if (half) {
            __syncthreads();             // all waves done reading lo-half
            const short8* s8 = (const short8*)W1 + 2048;
            short8* d8 = (short8*)lds;
#pragma unroll
            for (int it = 0; it < 8; ++it) d8[it * 256 + tid] = s8[it * 256 + tid];
            __syncthreads();
        }
#pragma unroll
        for (int ks = 0; ks < 4; ++ks) {
            short8 a[2], b[2];
#pragma unroll
            for (int mt = 0; mt < 2; ++mt) {
                int m = w * 32 + mt * 16 + lc;
                a[mt] = *(const short8*)(lds + m * 256 + (((ks * 4 + lg) ^ (m & 7)) * 16));
            }
#pragma unroll
            for (int nt = 0; nt < 2; ++nt) {
                int n = nt * 16 + lc;
                int slot = half * 16 + ks * 4 + lg;
                b[nt] = *(const short8*)(lds + 32768 + n * 512 + ((slot ^ (n & 7)) * 16));
            }
#pragma unroll
            for (int mt = 0; mt < 2; ++mt)
#pragma unroll
                for (int nt = 0; nt < 2; ++nt)
                    acc1[mt][nt] = __builtin_amdgcn_mfma_f32_16x16x32_bf16(
                        a[mt], b[nt], acc1[mt][nt], 0, 0, 0);
        }
    }

    // bias1 + relu + pack -> h1T [n=32][k=128] bf16, rows 256B, swizzled.
    {
#pragma unroll
        for (int mt = 0; mt < 2; ++mt) {
            int mbase = w * 32 + mt * 16 + lg * 4;       // D row = lg*4+r
            f32x4 bv = *(const f32x4*)(B1 + mbase);
#pragma unroll
            for (int nt = 0; nt < 2; ++nt) {
                int n = nt * 16 + lc;                    // D col
                short4v o;
#pragma unroll
                for (int r = 0; r < 4; ++r) {
                    float vv = acc1[mt][nt][r] + bv[r];
                    o[r] = f2bf(vv > 0.f ? vv : 0.f);
                }
                int byte = 49152 + n * 256 + (((mbase >> 3) ^ (n & 7)) * 16) + (mbase & 7) * 2;
                *(short4v*)(lds + byte) = o;
            }
        }
    }
    __syncthreads();

    // GEMM2: out2 = W2 @ h1 ; A from regs, B from h1T
    f32x4 acc2[2] = {};
#pragma unroll
    for (int ks = 0; ks < 4; ++ks) {
#pragma unroll
        for (int nt = 0; nt < 2; ++nt) {
            int n = nt * 16 + lc;
            short8 b = *(const short8*)(lds + 49152 + n * 256 + (((ks * 4 + lg) ^ (n & 7)) * 16));
            acc2[nt] = __builtin_amdgcn_mfma_f32_16x16x32_bf16(
                w2frag[ks], b, acc2[nt], 0, 0, 0);
        }
    }
    // bias2 + store bf16 [L][B][H2]
    {
        int mbase = w * 16 + lg * 4;
        f32x4 bv = *(const f32x4*)(B2 + mbase);
#pragma unroll
        for (int nt = 0; nt < 2; ++nt) {
            int l = nt * 16 + lc;
            short4v o;
#pragma unroll
            for (int r = 0; r < 4; ++r) o[r] = f2bf(acc2[nt][r] + bv[r]);
            *(short4v*)((char*)Out + (((size_t)l * NB + bb) * NH2 + mbase) * 2) = o;
        }
    }
}

// ---------------------------------------------------------------------------
// Kernel B: per (i,j) pair, S = Yj @ Xi^T (256x256, K=64) via bf16 MFMA.
// R9: (1) NO atomicAdd — each block writes partial[blockIdx.x]; final
// reduce_kernel sums (kills the 1024-block same-line atomic burst).
// (2) Yj afrag direct global->reg (R7-verified indexing) but KEEPING
// __launch_bounds__(256,2) so the allocator is NOT capped (R7's spill bug).
// LDS 32KB (Xi only, swizzled).
// ---------------------------------------------------------------------------
__global__ __launch_bounds__(256, 2) void score_kernel(
    const __hip_bfloat16* __restrict__ xg,   // [L][B][H2]
    const __hip_bfloat16* __restrict__ yh,   // [L][B][H2]
    float* __restrict__ partial)
{
    __shared__ short tiles[NB * NH2];        // Xi only, swizzled (32KB)
    __shared__ float red[4];

    const int tid  = threadIdx.x;
    const int lane = tid & 63;
    const int w    = tid >> 6;               // wave 0..3 -> p rows [w*64, w*64+64)
    const int i    = blockIdx.x & (NL - 1);
    const int j    = blockIdx.x >> 5;
    const int lc   = lane & 15, lg = lane >> 4;

    // A-fragments (Yj rows, single-use per wave): direct global->reg, issued first
    const char* Yg = (const char*)(yh + (size_t)j * (NB * NH2));
    short8 afrag[4][2];
#pragma unroll
    for (int mt = 0; mt < 4; ++mt) {
        int row = w * 64 + mt * 16 + lc;
#pragma unroll
        for (int ks = 0; ks < 2; ++ks)
            afrag[mt][ks] = *(const short8*)(Yg + row * 128 + ks * 64 + lg * 16);
    }

    // stage Xi tile (32KB) with XOR swizzle (row stride 128B -> G4 fix)
    {
        const short8* sx = (const short8*)(xg + (size_t)i * (NB * NH2));
        char* xb = (char*)tiles;
#pragma unroll
        for (int it = 0; it < 8; ++it) {
            int u   = it * 256 + tid;               // 16B unit, 0..2047
            int row = u >> 3;
            int swz = (u * 16) ^ ((row & 7) << 4);
            *(short8*)(xb + swz) = sx[u];
        }
    }
    __syncthreads();

    const char* Xbase = (const char*)tiles;

    float rowsum[4][4] = {};   // [mt][r], per-lane partial over owned cols
    float diag_acc = 0.f;

#pragma unroll
    for (int pn = 0; pn < 4; ++pn) {         // q-panel: cols [pn*64, pn*64+64)
        f32x4 acc[4][4] = {};                // [mt][nt]
#pragma unroll
        for (int nt = 0; nt < 4; ++nt) {
            int row = pn * 64 + nt * 16 + lc;  // Xi row = q
#pragma unroll
            for (int ks = 0; ks < 2; ++ks) {
                int byte = (row * 128 + ks * 64 + lg * 16) ^ ((row & 7) << 4);
                short8 bfrag = *(const short8*)(Xbase + byte);
#pragma unroll
                for (int mt = 0; mt < 4; ++mt)
                    acc[mt][nt] = __builtin_amdgcn_mfma_f32_16x16x32_bf16(
                        afrag[mt][ks], bfrag, acc[mt][nt], 0, 0, 0);
            }
        }
        // streamed exp-sum (no max subtraction: S is O(1), fp32-safe)
#pragma unroll
        for (int mt = 0; mt < 4; ++mt)
#pragma unroll
            for (int r = 0; r < 4; ++r) {
                float s = 0.f;
#pragma unroll
                for (int nt = 0; nt < 4; ++nt) s += __expf(acc[mt][nt][r]);
                rowsum[mt][r] += s;
            }
        // diag (p==q): only when this wave's row range == panel col range
        if (pn == w) {
#pragma unroll
            for (int mt = 0; mt < 4; ++mt)
#pragma unroll
                for (int r = 0; r < 4; ++r)
                    if (lc == lg * 4 + r) diag_acc += acc[mt][mt][r];
        }
    }

    // finish lse: reduce rowsum across the 16 col-lanes, then -log
    float neglog = 0.f;
#pragma unroll
    for (int mt = 0; mt < 4; ++mt)
#pragma unroll
        for (int r = 0; r < 4; ++r) {
            float v = rowsum[mt][r];
            v += __shfl_xor(v, 1);
            v += __shfl_xor(v, 2);
            v += __shfl_xor(v, 4);
            v += __shfl_xor(v, 8);
            neglog -= __logf(v);
        }
    float local = diag_acc + (lc == 0 ? neglog : 0.f);
    // wave reduce (64 lanes)
#pragma unroll
    for (int m = 32; m; m >>= 1) local += __shfl_xor(local, m);
    if (lane == 0) red[w] = local;
    __syncthreads();
    if (tid == 0)
        partial[blockIdx.x] = red[0] + red[1] + red[2] + red[3];
}

// ---------------------------------------------------------------------------
// Final reduce: 1 block, 256 threads, sums 1024 partials -> out[0].
// ---------------------------------------------------------------------------
__global__ __launch_bounds__(256) void reduce_kernel(
    const float* __restrict__ partial, float* __restrict__ out)
{
    __shared__ float r4[4];
    int tid = threadIdx.x;
    f32x4 v = *(const f32x4*)(partial + tid * 4);
    float s = v[0] + v[1] + v[2] + v[3];
#pragma unroll
    for (int m = 32; m; m >>= 1) s += __shfl_xor(s, m);
    if ((tid & 63) == 0) r4[tid >> 6] = s;
    __syncthreads();
    if (tid == 0)
        out[0] = logf(256.0f) + (r4[0] + r4[1] + r4[2] + r4[3]) * (1.0f / (1024.0f * 256.0f));
}

// ---------------------------------------------------------------------------
extern "C" void kernel_launch(void* const* d_in, const int* in_sizes, int n_in,
                              void* d_out, int out_size, void* d_ws, size_t ws_size,
                              hipStream_t stream)
{
    (void)in_sizes; (void)n_in; (void)out_size; (void)ws_size;
    const float* x   = (const float*)d_in[0];
    const float* y   = (const float*)d_in[1];
    const float* Wg1 = (const float*)d_in[2];
    const float* bg1 = (const float*)d_in[3];
    const float* Wg2 = (const float*)d_in[4];
    const float* bg2 = (const float*)d_in[5];
    const float* Wh1 = (const float*)d_in[6];
    const float* bh1 = (const float*)d_in[7];
    const float* Wh2 = (const float*)d_in[8];
    const float* bh2 = (const float*)d_in[9];

    char* ws = (char*)d_ws;
    __hip_bfloat16* xg  = (__hip_bfloat16*)ws;                    // 1MB
    __hip_bfloat16* yh  = (__hip_bfloat16*)(ws + (1 << 20));      // 1MB
    __hip_bfloat16* w1g = (__hip_bfloat16*)(ws + (2 << 20));      // 64KB (swizzled halves)
    __hip_bfloat16* w1h = (__hip_bfloat16*)(ws + (2 << 20) + 65536);
    __hip_bfloat16* w2g = (__hip_bfloat16*)(ws + (2 << 20) + 131072);  // 16KB plain
    __hip_bfloat16* w2h = (__hip_bfloat16*)(ws + (2 << 20) + 147456);
    float* partial = (float*)(ws + (2 << 20) + 262144);           // 4KB
    float* out = (float*)d_out;

    prep_kernel<<<dim3(40), dim3(256), 0, stream>>>(
        Wg1, Wg2, Wh1, Wh2, w1g, w1h, w2g, w2h);
    mlp_kernel<<<dim3(512), dim3(256), 0, stream>>>(
        x, y, bg1, bg2, bh1, bh2, w1g, w1h, w2g, w2h, xg, yh);
    score_kernel<<<dim3(1024), dim3(256), 0, stream>>>(xg, yh, partial);
    reduce_kernel<<<dim3(1), dim3(256), 0, stream>>>(partial, out);
}